// Round 17
// baseline (202.409 us; speedup 1.0000x reference)
//
#include <hip/hip_runtime.h>

#define N_NODE 100000
#define N_PAD  100064            // padded rows for OOB-safe fragment loads
#define N_EDGE 1000000
#define HID 64
#define ATTN 32
#define REL_VOCAB 2005

#define CBSHIFT 9
#define CBN    512               // nodes per coarse bucket
#define NCB    196               // ceil(N_NODE/CBN)
#define MAXCB  8192              // slots per bucket region (mean 5120, +43σ)
#define LCAP   6400              // LDS sort capacity (mean +18σ)
#define N_SLOT (NCB*MAXCB)       // 1,605,632 padded slots
#define ACHUNK 4096              // edges per k_part block

typedef short  bf16x8 __attribute__((ext_vector_type(8)));
typedef float  f32x4  __attribute__((ext_vector_type(4)));

__device__ __forceinline__ float sigf(float x){
  return __builtin_amdgcn_rcpf(1.0f + __expf(-x));
}
__device__ __forceinline__ float tanh_fast(float x){
  // 2*sigmoid(2x)-1; exact limits at +-inf, no NaN path, ~1e-6 rel err
  return fmaf(2.0f, __builtin_amdgcn_rcpf(1.0f + __expf(-2.0f*x)), -1.0f);
}
__device__ __forceinline__ float bf2f(unsigned short u){
  return __uint_as_float(((unsigned int)u) << 16);
}
__device__ __forceinline__ unsigned short f2bf(float f){  // RNE
  unsigned int x = __float_as_uint(f);
  x += 0x7fffu + ((x >> 16) & 1u);
  return (unsigned short)(x >> 16);
}
// wave-local LDS fence: xlds regions are per-wave private, so a full
// __syncthreads() is overkill — order ds_write -> ds_read within the wave.
__device__ __forceinline__ void wave_lds_fence(){
  asm volatile("s_waitcnt lgkmcnt(0)" ::: "memory");
  __builtin_amdgcn_sched_barrier(0);
}

__device__ __forceinline__ float dot64(const float4* a, const float4* __restrict__ w){
  float s0=0.f,s1=0.f,s2=0.f,s3=0.f;
  #pragma unroll
  for (int i=0;i<16;i++){
    float4 av=a[i]; float4 wv=w[i];
    s0=fmaf(av.x,wv.x,s0); s1=fmaf(av.y,wv.y,s1);
    s2=fmaf(av.z,wv.z,s2); s3=fmaf(av.w,wv.w,s3);
  }
  return (s0+s1)+(s2+s3);
}

// ---- per-relation precompute, wave-parallel: one wave per relation ----
__global__ void __launch_bounds__(256, 4) k_pre(
    const float* __restrict__ re, const float* __restrict__ Wr,
    const float* __restrict__ ww, const float* __restrict__ wb,
    unsigned short* __restrict__ srel16, unsigned short* __restrict__ re16,
    float* __restrict__ hrW1)
{
  int w = (blockIdx.x*blockDim.x + threadIdx.x) >> 6;
  int l = threadIdx.x & 63;
  if (w >= REL_VOCAB) return;
  const int r = w;
  const int j = l & 31;
  const bool hi = (l >= 32);

  float4 ev[16];
  const float4* ep = (const float4*)(re + (size_t)(hi ? REL_VOCAB + r : r)*HID);
  #pragma unroll
  for (int i=0;i<16;i++) ev[i]=ep[i];

  const float4* wrow = (const float4*)(Wr + (size_t)(hi ? ATTN + j : j)*HID);
  float d = dot64(ev, wrow);

  if (hi) hrW1[r*ATTN + j] = d;

  float p = hi ? 0.f : fmaxf(d, 0.f) * ww[j];
  p += __shfl_xor(p, 1);
  p += __shfl_xor(p, 2);
  p += __shfl_xor(p, 4);
  p += __shfl_xor(p, 8);
  p += __shfl_xor(p, 16);
  p += __shfl_xor(p, 32);
  float alpha = sigf(p + wb[0]);

  float e0l = re[(size_t)r*HID + l];
  float e1l = re[(size_t)(REL_VOCAB + r)*HID + l];
  srel16[r*HID + l] = f2bf(alpha * e0l);
  re16[r*HID + l]   = f2bf(e1l);
}

__global__ void k_izero(int* __restrict__ p, int n){
  int i = blockIdx.x*blockDim.x + threadIdx.x;
  if (i < n) p[i] = 0;
}

// ---- weight pack into bf16 MFMA B-fragment order ----
__global__ void k_wt(const float* __restrict__ Wh, const float* __restrict__ Wih,
                     const float* __restrict__ Whh, const float* __restrict__ Ws,
                     unsigned short* __restrict__ pkWh, unsigned short* __restrict__ pkWih,
                     unsigned short* __restrict__ pkWhh, unsigned short* __restrict__ pkWs)
{
  int tid = blockIdx.x*blockDim.x + threadIdx.x;
  if (tid >= 116*64) return;
  int rec = tid >> 6, l = tid & 63;
  const float* src; unsigned short* dst; int tile, c;
  if (rec < 16){
    int li = rec >> 3, q = rec & 7; tile = q >> 1; c = q & 1;
    src = Wh + li*4096;
    dst = pkWh + (size_t)((li*8 + q)*64 + l)*8;
  } else if (rec < 64){
    int q2 = rec - 16; int li = q2 / 24, q = q2 % 24; tile = q >> 1; c = q & 1;
    src = Wih + li*12288;
    dst = pkWih + (size_t)((li*24 + q)*64 + l)*8;
  } else if (rec < 112){
    int q2 = rec - 64; int li = q2 / 24, q = q2 % 24; tile = q >> 1; c = q & 1;
    src = Whh + li*12288;
    dst = pkWhh + (size_t)((li*24 + q)*64 + l)*8;
  } else {
    int q = rec - 112; tile = q >> 1; c = q & 1;
    src = Ws + ATTN*HID;                       // layer-1 Ws only
    dst = pkWs + (size_t)(q*64 + l)*8;
  }
  int row = tile*16 + (l&15);
  int k0  = c*32 + (l>>4)*8;
  #pragma unroll
  for (int j=0;j<8;j++) dst[j] = f2bf(src[row*64 + k0 + j]);
}

// ---- pass A: block-level partition into 196 coarse buckets ----
__global__ void __launch_bounds__(256, 4) k_part(
    const int* __restrict__ edges, int* __restrict__ gcursor,
    uint2* __restrict__ tmp)
{
  __shared__ int hcnt[NCB];
  __shared__ int hbase[NCB];
  __shared__ int hcur[NCB];
  const int t = threadIdx.x;
  const int base = blockIdx.x * ACHUNK;
  const int nE = min(ACHUNK, N_EDGE - base);

  if (t < NCB){ hcnt[t] = 0; }
  __syncthreads();

  unsigned pk[16]; int bb[16], lo[16];
  const int2* e2 = (const int2*)edges;
  #pragma unroll
  for (int j=0;j<16;j++){
    int idx = j*256 + t;
    if (idx < nE){
      int e = base + idx;
      int rel = e2[e*3+1].x;
      int2 so = e2[e*3+2];
      pk[j] = ((unsigned)rel << 17) | (unsigned)so.x;
      bb[j] = so.y >> CBSHIFT;
      lo[j] = so.y & (CBN-1);
      atomicAdd(&hcnt[bb[j]], 1);
    } else bb[j] = -1;
  }
  __syncthreads();
  if (t < NCB){
    hbase[t] = (hcnt[t] > 0) ? atomicAdd(&gcursor[t], hcnt[t]) : 0;
    hcur[t] = 0;
  }
  __syncthreads();
  #pragma unroll
  for (int j=0;j<16;j++){
    if (bb[j] >= 0){
      int pos = hbase[bb[j]] + atomicAdd(&hcur[bb[j]], 1);
      if (pos < MAXCB)
        tmp[(size_t)bb[j]*MAXCB + pos] = make_uint2(pk[j], (unsigned)lo[j]);
    }
  }
}

// ---- pass B: in-bucket counting sort, one block per coarse bucket ----
__global__ void __launch_bounds__(256, 2) k_bsort2(
    const uint2* __restrict__ tmp, const int* __restrict__ gcursor,
    unsigned int* __restrict__ pairP, int* __restrict__ startArr,
    int* __restrict__ endArr)
{
  __shared__ int lcnt[CBN];
  __shared__ int lsc[CBN];
  __shared__ int lcur[CBN];
  __shared__ unsigned int lout[LCAP];
  const int b = blockIdx.x, t = threadIdx.x;
  const int base = b*MAXCB;
  const int size = min(gcursor[b], LCAP);

  lcnt[t] = 0; lcnt[256+t] = 0;
  __syncthreads();
  for (int i=t; i<size; i+=256)
    atomicAdd(&lcnt[tmp[base+i].y], 1);
  __syncthreads();

  int cA = lcnt[t], cB = lcnt[256+t];
  lsc[t] = cA; lsc[256+t] = cB;
  __syncthreads();
  #pragma unroll
  for (int off=1; off<256; off<<=1){
    int vA = (t>=off) ? lsc[t-off] : 0;
    int vB = (t>=off) ? lsc[256+t-off] : 0;
    __syncthreads();
    lsc[t] += vA; lsc[256+t] += vB;
    __syncthreads();
  }
  int totA = lsc[255];
  __syncthreads();
  lsc[256+t] += totA;
  __syncthreads();

  {
    int inclA = lsc[t], exclA = inclA - cA;
    lcur[t] = exclA;
    int n = b*CBN + t;
    if (n < N_NODE){ startArr[n] = base + exclA; endArr[n] = base + inclA; }
    int inclB = lsc[256+t], exclB = inclB - cB;
    lcur[256+t] = exclB;
    int n2 = b*CBN + 256 + t;
    if (n2 < N_NODE){ startArr[n2] = base + exclB; endArr[n2] = base + inclB; }
  }
  __syncthreads();

  for (int i=t; i<size; i+=256){
    uint2 p = tmp[base+i];
    int pos = atomicAdd(&lcur[p.y], 1);
    lout[pos] = p.x;
  }
  __syncthreads();
  for (int i=t; i<size; i+=256)
    pairP[base+i] = lout[i];
}

// ---- layer-0 aggregation: wave per node; 8 independent gather chains ----
__global__ void k_agg0(const int* __restrict__ startArr, const int* __restrict__ endArr,
                       const unsigned int* __restrict__ pairP,
                       const unsigned short* __restrict__ srel16,
                       unsigned short* __restrict__ agg16)
{
  int t = blockIdx.x*blockDim.x + threadIdx.x;
  int n = __builtin_amdgcn_readfirstlane(t >> 6);
  int k = t & 63;
  if (n >= N_NODE) return;
  int b = startArr[n], e_ = endArr[n];
  float ac[8];
  #pragma unroll
  for (int j=0;j<8;j++) ac[j]=0.f;
  for (int i = b & ~7; i < e_; i += 8){
    uint4 pA = *(const uint4*)(pairP + i);
    uint4 pB = *(const uint4*)(pairP + i + 4);
    int r0 = min((int)(pA.x >> 17), REL_VOCAB-1);
    int r1 = min((int)(pA.y >> 17), REL_VOCAB-1);
    int r2 = min((int)(pA.z >> 17), REL_VOCAB-1);
    int r3 = min((int)(pA.w >> 17), REL_VOCAB-1);
    int r4 = min((int)(pB.x >> 17), REL_VOCAB-1);
    int r5 = min((int)(pB.y >> 17), REL_VOCAB-1);
    int r6 = min((int)(pB.z >> 17), REL_VOCAB-1);
    int r7 = min((int)(pB.w >> 17), REL_VOCAB-1);
    float v0 = bf2f(srel16[r0*HID+k]);
    float v1 = bf2f(srel16[r1*HID+k]);
    float v2 = bf2f(srel16[r2*HID+k]);
    float v3 = bf2f(srel16[r3*HID+k]);
    float v4 = bf2f(srel16[r4*HID+k]);
    float v5 = bf2f(srel16[r5*HID+k]);
    float v6 = bf2f(srel16[r6*HID+k]);
    float v7 = bf2f(srel16[r7*HID+k]);
    ac[0] += (i+0>=b && i+0<e_) ? v0 : 0.f;
    ac[1] += (i+1>=b && i+1<e_) ? v1 : 0.f;
    ac[2] += (i+2>=b && i+2<e_) ? v2 : 0.f;
    ac[3] += (i+3>=b && i+3<e_) ? v3 : 0.f;
    ac[4] += (i+4>=b && i+4<e_) ? v4 : 0.f;
    ac[5] += (i+5>=b && i+5<e_) ? v5 : 0.f;
    ac[6] += (i+6>=b && i+6<e_) ? v6 : 0.f;
    ac[7] += (i+7>=b && i+7<e_) ? v7 : 0.f;
  }
  float s = ((ac[0]+ac[1])+(ac[2]+ac[3])) + ((ac[4]+ac[5])+(ac[6]+ac[7]));
  agg16[(size_t)n*HID + k] = f2bf(s);
}

// ---- layer-1 per-edge alpha via MFMA: wave = 16 slots ----
__global__ void __launch_bounds__(256, 4) k_alphaM(
    const unsigned int* __restrict__ pairP, const int* __restrict__ gcursor,
    const unsigned short* __restrict__ h16,
    const float* __restrict__ hrW1, const unsigned short* __restrict__ pkWs,
    const float* __restrict__ ww1, const float* __restrict__ wb1,
    float* __restrict__ alphaS)
{
  const int t = threadIdx.x;
  const int w = t >> 6, l = t & 63;
  const int lr = l & 15, lg = l >> 4;
  const int i0 = (blockIdx.x*4 + w) * 16;      // N_SLOT = 64 * gridDim
  const int bkt   = i0 >> 13;                  // MAXCB = 8192 slots/bucket
  const int local = i0 & (MAXCB-1);
  const int size  = min(gcursor[bkt], LCAP);
  if (local >= size) return;                   // wave-uniform

  unsigned pe = pairP[i0 + lr];
  int subA = min((int)(pe & 0x1FFFFu), N_NODE-1);
  bf16x8 a0 = *(const bf16x8*)(h16 + (size_t)subA*HID + lg*8);
  bf16x8 a1 = *(const bf16x8*)(h16 + (size_t)subA*HID + 32 + lg*8);

  bf16x8 b00 = *(const bf16x8*)(pkWs + (size_t)(0*64 + l)*8);
  bf16x8 b01 = *(const bf16x8*)(pkWs + (size_t)(1*64 + l)*8);
  bf16x8 b10 = *(const bf16x8*)(pkWs + (size_t)(2*64 + l)*8);
  bf16x8 b11 = *(const bf16x8*)(pkWs + (size_t)(3*64 + l)*8);

  f32x4 acc0 = {0.f,0.f,0.f,0.f}, acc1 = {0.f,0.f,0.f,0.f};
  acc0 = __builtin_amdgcn_mfma_f32_16x16x32_bf16(a0, b00, acc0, 0,0,0);
  acc0 = __builtin_amdgcn_mfma_f32_16x16x32_bf16(a1, b01, acc0, 0,0,0);
  acc1 = __builtin_amdgcn_mfma_f32_16x16x32_bf16(a0, b10, acc1, 0,0,0);
  acc1 = __builtin_amdgcn_mfma_f32_16x16x32_bf16(a1, b11, acc1, 0,0,0);

  float wlo = ww1[lr], whi = ww1[16 + lr];
  float bias = wb1[0];
  float s[4];
  #pragma unroll
  for (int r=0;r<4;r++){
    int e = i0 + lg*4 + r;
    int rel = min((int)(pairP[e] >> 17), REL_VOCAB-1);
    float v0 = fmaxf(acc0[r] + hrW1[rel*ATTN + lr],      0.f);
    float v1 = fmaxf(acc1[r] + hrW1[rel*ATTN + 16 + lr], 0.f);
    float p = fmaf(v0, wlo, v1*whi);
    p += __shfl_xor(p, 1);
    p += __shfl_xor(p, 2);
    p += __shfl_xor(p, 4);
    p += __shfl_xor(p, 8);
    s[r] = sigf(p + bias);
  }
  if (lr == 0)
    *(float4*)(alphaS + i0 + lg*4) = make_float4(s[0], s[1], s[2], s[3]);
}

// ---- layer-1 aggregation: wave per node; 8 independent gather chains ----
__global__ void k_agg1(const int* __restrict__ startArr, const int* __restrict__ endArr,
                       const unsigned int* __restrict__ pairP,
                       const float* __restrict__ alphaS,
                       const unsigned short* __restrict__ h16,
                       const unsigned short* __restrict__ re16,
                       unsigned short* __restrict__ agg16)
{
  int t = blockIdx.x*blockDim.x + threadIdx.x;
  int n = __builtin_amdgcn_readfirstlane(t >> 6);
  int k = t & 63;
  if (n >= N_NODE) return;
  int b = startArr[n], e_ = endArr[n];
  float ac[8];
  #pragma unroll
  for (int j=0;j<8;j++) ac[j]=0.f;
  for (int i = b & ~7; i < e_; i += 8){
    uint4  pA = *(const uint4*)(pairP + i);
    uint4  pB = *(const uint4*)(pairP + i + 4);
    float4 aA = *(const float4*)(alphaS + i);
    float4 aB = *(const float4*)(alphaS + i + 4);
    int s0 = min((int)(pA.x & 0x1FFFFu), N_NODE-1);
    int s1 = min((int)(pA.y & 0x1FFFFu), N_NODE-1);
    int s2 = min((int)(pA.z & 0x1FFFFu), N_NODE-1);
    int s3 = min((int)(pA.w & 0x1FFFFu), N_NODE-1);
    int s4 = min((int)(pB.x & 0x1FFFFu), N_NODE-1);
    int s5 = min((int)(pB.y & 0x1FFFFu), N_NODE-1);
    int s6 = min((int)(pB.z & 0x1FFFFu), N_NODE-1);
    int s7 = min((int)(pB.w & 0x1FFFFu), N_NODE-1);
    int r0 = min((int)(pA.x >> 17), REL_VOCAB-1);
    int r1 = min((int)(pA.y >> 17), REL_VOCAB-1);
    int r2 = min((int)(pA.z >> 17), REL_VOCAB-1);
    int r3 = min((int)(pA.w >> 17), REL_VOCAB-1);
    int r4 = min((int)(pB.x >> 17), REL_VOCAB-1);
    int r5 = min((int)(pB.y >> 17), REL_VOCAB-1);
    int r6 = min((int)(pB.z >> 17), REL_VOCAB-1);
    int r7 = min((int)(pB.w >> 17), REL_VOCAB-1);
    float h0 = bf2f(h16[(size_t)s0*HID + k]);
    float h1 = bf2f(h16[(size_t)s1*HID + k]);
    float h2 = bf2f(h16[(size_t)s2*HID + k]);
    float h3 = bf2f(h16[(size_t)s3*HID + k]);
    float h4 = bf2f(h16[(size_t)s4*HID + k]);
    float h5 = bf2f(h16[(size_t)s5*HID + k]);
    float h6 = bf2f(h16[(size_t)s6*HID + k]);
    float h7 = bf2f(h16[(size_t)s7*HID + k]);
    float v0 = bf2f(re16[r0*HID + k]);
    float v1 = bf2f(re16[r1*HID + k]);
    float v2 = bf2f(re16[r2*HID + k]);
    float v3 = bf2f(re16[r3*HID + k]);
    float v4 = bf2f(re16[r4*HID + k]);
    float v5 = bf2f(re16[r5*HID + k]);
    float v6 = bf2f(re16[r6*HID + k]);
    float v7 = bf2f(re16[r7*HID + k]);
    float al0 = (i+0>=b && i+0<e_) ? aA.x : 0.f;
    float al1 = (i+1>=b && i+1<e_) ? aA.y : 0.f;
    float al2 = (i+2>=b && i+2<e_) ? aA.z : 0.f;
    float al3 = (i+3>=b && i+3<e_) ? aA.w : 0.f;
    float al4 = (i+4>=b && i+4<e_) ? aB.x : 0.f;
    float al5 = (i+5>=b && i+5<e_) ? aB.y : 0.f;
    float al6 = (i+6>=b && i+6<e_) ? aB.z : 0.f;
    float al7 = (i+7>=b && i+7<e_) ? aB.w : 0.f;
    ac[0] = fmaf(al0, h0+v0, ac[0]);
    ac[1] = fmaf(al1, h1+v1, ac[1]);
    ac[2] = fmaf(al2, h2+v2, ac[2]);
    ac[3] = fmaf(al3, h3+v3, ac[3]);
    ac[4] = fmaf(al4, h4+v4, ac[4]);
    ac[5] = fmaf(al5, h5+v5, ac[5]);
    ac[6] = fmaf(al6, h6+v6, ac[6]);
    ac[7] = fmaf(al7, h7+v7, ac[7]);
  }
  float s = ((ac[0]+ac[1])+(ac[2]+ac[3])) + ((ac[4]+ac[5])+(ac[6]+ac[7]));
  agg16[(size_t)n*HID + k] = f2bf(s);
}

// ---- MFMA node phase: 64 nodes/block, wave w owns nodes w*16..w*16+15 ----
// xlds regions are PER-WAVE private -> no __syncthreads anywhere; waves run
// fully independently (wave_lds_fence orders write->read within the wave).
template<int HAS_H0>
__global__ void __launch_bounds__(256, 4) k_node2(
    const unsigned short* __restrict__ agg16,
    const unsigned short* __restrict__ h16,
    const unsigned short* __restrict__ pkWh,
    const unsigned short* __restrict__ pkWih,
    const unsigned short* __restrict__ pkWhh,
    const float* __restrict__ bih, const float* __restrict__ bhh,
    unsigned short* __restrict__ h16_out,
    const float* __restrict__ wf, float* __restrict__ score, int mode)
{
  __shared__ unsigned short xlds[4096];   // 4 waves x [16 rows][64 cols] bf16, swizzled

  const int t  = threadIdx.x;
  const int w  = t >> 6, l = t & 63;
  const int lr = l & 15;                  // fragment row/col
  const int lg = l >> 4;                  // k-group
  const int n0 = blockIdx.x * 64;
  const int rowA = n0 + w*16 + lr;

  bf16x8 aA0 = *(const bf16x8*)(agg16 + (size_t)rowA*HID + lg*8);
  bf16x8 aA1 = *(const bf16x8*)(agg16 + (size_t)rowA*HID + 32 + lg*8);
  bf16x8 hA0, hA1;
  if (HAS_H0){
    hA0 = *(const bf16x8*)(h16 + (size_t)rowA*HID + lg*8);
    hA1 = *(const bf16x8*)(h16 + (size_t)rowA*HID + 32 + lg*8);
  }

  float bir[4],biz[4],bin[4],bhr[4],bhz[4],bhn[4],wfv[4];
  #pragma unroll
  for (int nt=0;nt<4;nt++){
    int ch = nt*16 + lr;
    bir[nt]=bih[ch]; biz[nt]=bih[64+ch]; bin[nt]=bih[128+ch];
    bhr[nt]=bhh[ch]; bhz[nt]=bhh[64+ch]; bhn[nt]=bhh[128+ch];
    wfv[nt]=wf[ch];
  }

  // ---- X = relu(agg @ Wh^T) ----
  #pragma unroll
  for (int nt=0;nt<4;nt++){
    f32x4 acc = {0.f,0.f,0.f,0.f};
    bf16x8 b0 = *(const bf16x8*)(pkWh + (size_t)((nt*2+0)*64 + l)*8);
    bf16x8 b1 = *(const bf16x8*)(pkWh + (size_t)((nt*2+1)*64 + l)*8);
    acc = __builtin_amdgcn_mfma_f32_16x16x32_bf16(aA0, b0, acc, 0,0,0);
    acc = __builtin_amdgcn_mfma_f32_16x16x32_bf16(aA1, b1, acc, 0,0,0);
    #pragma unroll
    for (int r=0;r<4;r++){
      int m = lg*4 + r, col = nt*16 + lr;
      xlds[w*1024 + m*64 + (col ^ ((m&7)<<3))] = f2bf(fmaxf(acc[r], 0.f));
    }
  }
  wave_lds_fence();

  const int xbase = w*1024 + lr*64;
  const int sw = (lr&7)<<3;
  bf16x8 xA0 = *(const bf16x8*)&xlds[xbase + ((lg*8)      ^ sw)];
  bf16x8 xA1 = *(const bf16x8*)&xlds[xbase + ((32 + lg*8) ^ sw)];

  // ---- gate passes ----
  float rv[16], zv[16], hv[16];
  #pragma unroll
  for (int g=0; g<2; ++g){               // g=0: r-gate, g=1: z-gate
    #pragma unroll
    for (int nt=0;nt<4;nt++){
      int gt = g*4 + nt;
      f32x4 ai = {0.f,0.f,0.f,0.f};
      bf16x8 bi0 = *(const bf16x8*)(pkWih + (size_t)((gt*2+0)*64 + l)*8);
      bf16x8 bi1 = *(const bf16x8*)(pkWih + (size_t)((gt*2+1)*64 + l)*8);
      ai = __builtin_amdgcn_mfma_f32_16x16x32_bf16(xA0, bi0, ai, 0,0,0);
      ai = __builtin_amdgcn_mfma_f32_16x16x32_bf16(xA1, bi1, ai, 0,0,0);
      f32x4 ah = {0.f,0.f,0.f,0.f};
      if (HAS_H0){
        bf16x8 bh0 = *(const bf16x8*)(pkWhh + (size_t)((gt*2+0)*64 + l)*8);
        bf16x8 bh1 = *(const bf16x8*)(pkWhh + (size_t)((gt*2+1)*64 + l)*8);
        ah = __builtin_amdgcn_mfma_f32_16x16x32_bf16(hA0, bh0, ah, 0,0,0);
        ah = __builtin_amdgcn_mfma_f32_16x16x32_bf16(hA1, bh1, ah, 0,0,0);
      }
      #pragma unroll
      for (int r=0;r<4;r++){
        float bi_ = (g==0) ? bir[nt] : biz[nt];
        float bh_ = (g==0) ? bhr[nt] : bhz[nt];
        float v = sigf(ai[r] + bi_ + ah[r] + bh_);
        if (g==0) rv[nt*4+r] = v; else zv[nt*4+r] = v;
      }
    }
  }
  #pragma unroll
  for (int nt=0;nt<4;nt++){              // n-gate + GRU blend
    int gt = 8 + nt;
    f32x4 ai = {0.f,0.f,0.f,0.f};
    bf16x8 bi0 = *(const bf16x8*)(pkWih + (size_t)((gt*2+0)*64 + l)*8);
    bf16x8 bi1 = *(const bf16x8*)(pkWih + (size_t)((gt*2+1)*64 + l)*8);
    ai = __builtin_amdgcn_mfma_f32_16x16x32_bf16(xA0, bi0, ai, 0,0,0);
    ai = __builtin_amdgcn_mfma_f32_16x16x32_bf16(xA1, bi1, ai, 0,0,0);
    f32x4 ah = {0.f,0.f,0.f,0.f};
    if (HAS_H0){
      bf16x8 bh0 = *(const bf16x8*)(pkWhh + (size_t)((gt*2+0)*64 + l)*8);
      bf16x8 bh1 = *(const bf16x8*)(pkWhh + (size_t)((gt*2+1)*64 + l)*8);
      ah = __builtin_amdgcn_mfma_f32_16x16x32_bf16(hA0, bh0, ah, 0,0,0);
      ah = __builtin_amdgcn_mfma_f32_16x16x32_bf16(hA1, bh1, ah, 0,0,0);
    }
    #pragma unroll
    for (int r=0;r<4;r++){
      float gin = ai[r] + bin[nt];
      float ghn = ah[r] + bhn[nt];
      float rr  = rv[nt*4+r];
      float nn  = tanh_fast(fmaf(rr, ghn, gin));
      float z   = zv[nt*4+r];
      float h0v = 0.f;
      if (HAS_H0)
        h0v = bf2f(h16[(size_t)(n0 + w*16 + lg*4 + r)*HID + nt*16 + lr]);
      hv[nt*4+r] = (1.f - z)*nn + z*h0v;
    }
  }

  if (mode == 0){
    // xA0/xA1 already hold all xlds data this wave needs; safe to overwrite
    // own region (in-wave DS ordering + compiler alias ordering).
    #pragma unroll
    for (int nt=0;nt<4;nt++)
      #pragma unroll
      for (int r=0;r<4;r++){
        int m = lg*4 + r, col = nt*16 + lr;
        xlds[w*1024 + m*64 + (col ^ ((m&7)<<3))] = f2bf(hv[nt*4+r]);
      }
    wave_lds_fence();
    int rr2 = l >> 2, cc = l & 3;
    int n = n0 + w*16 + rr2;
    if (n < N_NODE){
      int base = w*1024 + rr2*64, s2 = (rr2&7)<<3;
      bf16x8 v0 = *(const bf16x8*)&xlds[base + ((cc*16)     ^ s2)];
      bf16x8 v1 = *(const bf16x8*)&xlds[base + ((cc*16 + 8) ^ s2)];
      *(bf16x8*)(h16_out + (size_t)n*HID + cc*16)     = v0;
      *(bf16x8*)(h16_out + (size_t)n*HID + cc*16 + 8) = v1;
    }
  } else {
    #pragma unroll
    for (int r=0;r<4;r++){
      float p = 0.f;
      #pragma unroll
      for (int nt=0;nt<4;nt++) p = fmaf(hv[nt*4+r], wfv[nt], p);
      p += __shfl_xor(p, 1);
      p += __shfl_xor(p, 2);
      p += __shfl_xor(p, 4);
      p += __shfl_xor(p, 8);
      if (lr == 0){
        int n = n0 + w*16 + lg*4 + r;
        if (n < N_NODE) score[n] = p;
      }
    }
  }
}

extern "C" void kernel_launch(void* const* d_in, const int* in_sizes, int n_in,
                              void* d_out, int out_size, void* d_ws, size_t ws_size,
                              hipStream_t stream)
{
  const int*   edges = (const int*)  d_in[0];
  const float* re    = (const float*)d_in[1];
  const float* Ws    = (const float*)d_in[2];
  const float* Wr    = (const float*)d_in[3];
  const float* ww    = (const float*)d_in[4];
  const float* wb    = (const float*)d_in[5];
  const float* Wh    = (const float*)d_in[6];
  const float* Wih   = (const float*)d_in[7];
  const float* Whh   = (const float*)d_in[8];
  const float* bih   = (const float*)d_in[9];
  const float* bhh   = (const float*)d_in[10];
  const float* wf    = (const float*)d_in[11];
  float* out = (float*)d_out;

  // workspace layout
  unsigned short* agg16  = (unsigned short*)d_ws;              // N_PAD*HID
  unsigned short* h16    = agg16 + (size_t)N_PAD*HID;          // N_PAD*HID
  unsigned short* srel16 = h16 + (size_t)N_PAD*HID;            // REL_VOCAB*HID
  unsigned short* re16   = srel16 + REL_VOCAB*HID;             // REL_VOCAB*HID
  unsigned short* pkWh   = re16 + REL_VOCAB*HID;               // 2*4096
  unsigned short* pkWih  = pkWh  + 2*4096;                     // 2*12288
  unsigned short* pkWhh  = pkWih + 2*12288;                    // 2*12288
  unsigned short* pkWs   = pkWhh + 2*12288;                    // 2048
  float* hrW1      = (float*)(pkWs + 2048);                    // REL_VOCAB*ATTN
  float* alphaS    = hrW1 + REL_VOCAB*ATTN;                    // N_SLOT
  uint2* tmp       = (uint2*)(alphaS + N_SLOT);                // N_SLOT uint2
  unsigned int* pairP = (unsigned int*)(tmp + N_SLOT);         // N_SLOT uint
  int*   startArr  = (int*)(pairP + N_SLOT);                   // NCB*CBN
  int*   endArr    = startArr + NCB*CBN;                       // NCB*CBN
  int*   gcursor   = endArr + NCB*CBN;                         // 256 (pad)

  // ---- two-pass bucket sort of edges by obj ----
  k_izero<<<1, 256, 0, stream>>>(gcursor, 256);
  k_part<<<(N_EDGE + ACHUNK - 1)/ACHUNK, 256, 0, stream>>>(edges, gcursor, tmp);
  k_bsort2<<<NCB, 256, 0, stream>>>(tmp, gcursor, pairP, startArr, endArr);

  // ---- per-relation tables + packed bf16 weights ----
  k_pre<<<(REL_VOCAB*64+255)/256, 256, 0, stream>>>(re, Wr, ww, wb, srel16, re16, hrW1);
  k_wt<<<(116*64+255)/256, 256, 0, stream>>>(Wh, Wih, Whh, Ws, pkWh, pkWih, pkWhh, pkWs);

  const int NB_NODE2 = (N_NODE + 63) / 64;

  // ---- layer 0 ----
  k_agg0<<<(N_NODE*64)/256, 256, 0, stream>>>(startArr, endArr, pairP, srel16, agg16);
  k_node2<0><<<NB_NODE2, 256, 0, stream>>>(agg16, h16,
        pkWh, pkWih, pkWhh, bih, bhh, h16, wf, out, 0);

  // ---- layer 1 ----
  k_alphaM<<<N_SLOT/64, 256, 0, stream>>>(pairP, gcursor, h16, hrW1, pkWs,
        ww + ATTN, wb + 1, alphaS);
  k_agg1<<<(N_NODE*64)/256, 256, 0, stream>>>(startArr, endArr, pairP, alphaS,
        h16, re16, agg16);
  k_node2<1><<<NB_NODE2, 256, 0, stream>>>(agg16, h16,
        pkWh + 4096, pkWih + 12288, pkWhh + 12288, bih + 3*HID, bhh + 3*HID,
        h16, wf, out, 1);
}

// Round 18
// 196.139 us; speedup vs baseline: 1.0320x; 1.0320x over previous
//
#include <hip/hip_runtime.h>

#define N_NODE 100000
#define N_PAD  100064            // padded rows for OOB-safe fragment loads
#define N_EDGE 1000000
#define HID 64
#define ATTN 32
#define REL_VOCAB 2005

#define CBSHIFT 9
#define CBN    512               // nodes per coarse bucket
#define NCB    196               // ceil(N_NODE/CBN)
#define MAXCB  8192              // slots per bucket region (mean 5120, +43σ)
#define LCAP   6400              // LDS sort capacity (mean +18σ)
#define N_SLOT (NCB*MAXCB)       // 1,605,632 padded slots
#define ACHUNK 4096              // edges per k_part block

typedef short  bf16x8 __attribute__((ext_vector_type(8)));
typedef float  f32x4  __attribute__((ext_vector_type(4)));

__device__ __forceinline__ float sigf(float x){
  return __builtin_amdgcn_rcpf(1.0f + __expf(-x));
}
__device__ __forceinline__ float tanh_fast(float x){
  // 2*sigmoid(2x)-1; exact limits at +-inf, no NaN path, ~1e-6 rel err
  return fmaf(2.0f, __builtin_amdgcn_rcpf(1.0f + __expf(-2.0f*x)), -1.0f);
}
__device__ __forceinline__ float bf2f(unsigned short u){
  return __uint_as_float(((unsigned int)u) << 16);
}
__device__ __forceinline__ unsigned short f2bf(float f){  // RNE
  unsigned int x = __float_as_uint(f);
  x += 0x7fffu + ((x >> 16) & 1u);
  return (unsigned short)(x >> 16);
}
// wave-local LDS fence: xlds regions are per-wave private, so a full
// __syncthreads() is overkill — order ds_write -> ds_read within the wave.
__device__ __forceinline__ void wave_lds_fence(){
  asm volatile("s_waitcnt lgkmcnt(0)" ::: "memory");
  __builtin_amdgcn_sched_barrier(0);
}

__device__ __forceinline__ float dot64(const float4* a, const float4* __restrict__ w){
  float s0=0.f,s1=0.f,s2=0.f,s3=0.f;
  #pragma unroll
  for (int i=0;i<16;i++){
    float4 av=a[i]; float4 wv=w[i];
    s0=fmaf(av.x,wv.x,s0); s1=fmaf(av.y,wv.y,s1);
    s2=fmaf(av.z,wv.z,s2); s3=fmaf(av.w,wv.w,s3);
  }
  return (s0+s1)+(s2+s3);
}

// ---- per-relation precompute, wave-parallel: one wave per relation ----
__global__ void __launch_bounds__(256, 4) k_pre(
    const float* __restrict__ re, const float* __restrict__ Wr,
    const float* __restrict__ ww, const float* __restrict__ wb,
    unsigned short* __restrict__ srel16, unsigned short* __restrict__ re16,
    float* __restrict__ hrW1)
{
  int w = (blockIdx.x*blockDim.x + threadIdx.x) >> 6;
  int l = threadIdx.x & 63;
  if (w >= REL_VOCAB) return;
  const int r = w;
  const int j = l & 31;
  const bool hi = (l >= 32);

  float4 ev[16];
  const float4* ep = (const float4*)(re + (size_t)(hi ? REL_VOCAB + r : r)*HID);
  #pragma unroll
  for (int i=0;i<16;i++) ev[i]=ep[i];

  const float4* wrow = (const float4*)(Wr + (size_t)(hi ? ATTN + j : j)*HID);
  float d = dot64(ev, wrow);

  if (hi) hrW1[r*ATTN + j] = d;

  float p = hi ? 0.f : fmaxf(d, 0.f) * ww[j];
  p += __shfl_xor(p, 1);
  p += __shfl_xor(p, 2);
  p += __shfl_xor(p, 4);
  p += __shfl_xor(p, 8);
  p += __shfl_xor(p, 16);
  p += __shfl_xor(p, 32);
  float alpha = sigf(p + wb[0]);

  float e0l = re[(size_t)r*HID + l];
  float e1l = re[(size_t)(REL_VOCAB + r)*HID + l];
  srel16[r*HID + l] = f2bf(alpha * e0l);
  re16[r*HID + l]   = f2bf(e1l);
}

__global__ void k_izero(int* __restrict__ p, int n){
  int i = blockIdx.x*blockDim.x + threadIdx.x;
  if (i < n) p[i] = 0;
}

// ---- weight pack into bf16 MFMA B-fragment order ----
__global__ void k_wt(const float* __restrict__ Wh, const float* __restrict__ Wih,
                     const float* __restrict__ Whh, const float* __restrict__ Ws,
                     unsigned short* __restrict__ pkWh, unsigned short* __restrict__ pkWih,
                     unsigned short* __restrict__ pkWhh, unsigned short* __restrict__ pkWs)
{
  int tid = blockIdx.x*blockDim.x + threadIdx.x;
  if (tid >= 116*64) return;
  int rec = tid >> 6, l = tid & 63;
  const float* src; unsigned short* dst; int tile, c;
  if (rec < 16){
    int li = rec >> 3, q = rec & 7; tile = q >> 1; c = q & 1;
    src = Wh + li*4096;
    dst = pkWh + (size_t)((li*8 + q)*64 + l)*8;
  } else if (rec < 64){
    int q2 = rec - 16; int li = q2 / 24, q = q2 % 24; tile = q >> 1; c = q & 1;
    src = Wih + li*12288;
    dst = pkWih + (size_t)((li*24 + q)*64 + l)*8;
  } else if (rec < 112){
    int q2 = rec - 64; int li = q2 / 24, q = q2 % 24; tile = q >> 1; c = q & 1;
    src = Whh + li*12288;
    dst = pkWhh + (size_t)((li*24 + q)*64 + l)*8;
  } else {
    int q = rec - 112; tile = q >> 1; c = q & 1;
    src = Ws + ATTN*HID;                       // layer-1 Ws only
    dst = pkWs + (size_t)(q*64 + l)*8;
  }
  int row = tile*16 + (l&15);
  int k0  = c*32 + (l>>4)*8;
  #pragma unroll
  for (int j=0;j<8;j++) dst[j] = f2bf(src[row*64 + k0 + j]);
}

// ---- pass A: block-level partition into 196 coarse buckets ----
__global__ void __launch_bounds__(256, 4) k_part(
    const int* __restrict__ edges, int* __restrict__ gcursor,
    uint2* __restrict__ tmp)
{
  __shared__ int hcnt[NCB];
  __shared__ int hbase[NCB];
  __shared__ int hcur[NCB];
  const int t = threadIdx.x;
  const int base = blockIdx.x * ACHUNK;
  const int nE = min(ACHUNK, N_EDGE - base);

  if (t < NCB){ hcnt[t] = 0; }
  __syncthreads();

  unsigned pk[16]; int bb[16], lo[16];
  const int2* e2 = (const int2*)edges;
  #pragma unroll
  for (int j=0;j<16;j++){
    int idx = j*256 + t;
    if (idx < nE){
      int e = base + idx;
      int rel = e2[e*3+1].x;
      int2 so = e2[e*3+2];
      pk[j] = ((unsigned)rel << 17) | (unsigned)so.x;
      bb[j] = so.y >> CBSHIFT;
      lo[j] = so.y & (CBN-1);
      atomicAdd(&hcnt[bb[j]], 1);
    } else bb[j] = -1;
  }
  __syncthreads();
  if (t < NCB){
    hbase[t] = (hcnt[t] > 0) ? atomicAdd(&gcursor[t], hcnt[t]) : 0;
    hcur[t] = 0;
  }
  __syncthreads();
  #pragma unroll
  for (int j=0;j<16;j++){
    if (bb[j] >= 0){
      int pos = hbase[bb[j]] + atomicAdd(&hcur[bb[j]], 1);
      if (pos < MAXCB)
        tmp[(size_t)bb[j]*MAXCB + pos] = make_uint2(pk[j], (unsigned)lo[j]);
    }
  }
}

// ---- pass B: in-bucket counting sort, one block per coarse bucket ----
__global__ void __launch_bounds__(256, 2) k_bsort2(
    const uint2* __restrict__ tmp, const int* __restrict__ gcursor,
    unsigned int* __restrict__ pairP, int* __restrict__ startArr,
    int* __restrict__ endArr)
{
  __shared__ int lcnt[CBN];
  __shared__ int lsc[CBN];
  __shared__ int lcur[CBN];
  __shared__ unsigned int lout[LCAP];
  const int b = blockIdx.x, t = threadIdx.x;
  const int base = b*MAXCB;
  const int size = min(gcursor[b], LCAP);

  lcnt[t] = 0; lcnt[256+t] = 0;
  __syncthreads();
  for (int i=t; i<size; i+=256)
    atomicAdd(&lcnt[tmp[base+i].y], 1);
  __syncthreads();

  int cA = lcnt[t], cB = lcnt[256+t];
  lsc[t] = cA; lsc[256+t] = cB;
  __syncthreads();
  #pragma unroll
  for (int off=1; off<256; off<<=1){
    int vA = (t>=off) ? lsc[t-off] : 0;
    int vB = (t>=off) ? lsc[256+t-off] : 0;
    __syncthreads();
    lsc[t] += vA; lsc[256+t] += vB;
    __syncthreads();
  }
  int totA = lsc[255];
  __syncthreads();
  lsc[256+t] += totA;
  __syncthreads();

  {
    int inclA = lsc[t], exclA = inclA - cA;
    lcur[t] = exclA;
    int n = b*CBN + t;
    if (n < N_NODE){ startArr[n] = base + exclA; endArr[n] = base + inclA; }
    int inclB = lsc[256+t], exclB = inclB - cB;
    lcur[256+t] = exclB;
    int n2 = b*CBN + 256 + t;
    if (n2 < N_NODE){ startArr[n2] = base + exclB; endArr[n2] = base + inclB; }
  }
  __syncthreads();

  for (int i=t; i<size; i+=256){
    uint2 p = tmp[base+i];
    int pos = atomicAdd(&lcur[p.y], 1);
    lout[pos] = p.x;
  }
  __syncthreads();
  for (int i=t; i<size; i+=256)
    pairP[base+i] = lout[i];
}

// ---- layer-0 aggregation: wave per node; uint4 index stream, 4 chains ----
__global__ void k_agg0(const int* __restrict__ startArr, const int* __restrict__ endArr,
                       const unsigned int* __restrict__ pairP,
                       const unsigned short* __restrict__ srel16,
                       unsigned short* __restrict__ agg16)
{
  int t = blockIdx.x*blockDim.x + threadIdx.x;
  int n = __builtin_amdgcn_readfirstlane(t >> 6);
  int k = t & 63;
  if (n >= N_NODE) return;
  int b = startArr[n], e_ = endArr[n];
  float ac0=0.f, ac1=0.f, ac2=0.f, ac3=0.f;
  for (int i = b & ~3; i < e_; i += 4){
    uint4 p4 = *(const uint4*)(pairP + i);
    int r0 = min((int)(p4.x >> 17), REL_VOCAB-1);
    int r1 = min((int)(p4.y >> 17), REL_VOCAB-1);
    int r2 = min((int)(p4.z >> 17), REL_VOCAB-1);
    int r3 = min((int)(p4.w >> 17), REL_VOCAB-1);
    float v0 = bf2f(srel16[r0*HID+k]);
    float v1 = bf2f(srel16[r1*HID+k]);
    float v2 = bf2f(srel16[r2*HID+k]);
    float v3 = bf2f(srel16[r3*HID+k]);
    ac0 += (i+0>=b && i+0<e_) ? v0 : 0.f;
    ac1 += (i+1>=b && i+1<e_) ? v1 : 0.f;
    ac2 += (i+2>=b && i+2<e_) ? v2 : 0.f;
    ac3 += (i+3>=b && i+3<e_) ? v3 : 0.f;
  }
  agg16[(size_t)n*HID + k] = f2bf((ac0+ac1)+(ac2+ac3));
}

// ---- layer-1 per-edge alpha via MFMA: wave = 16 slots ----
__global__ void __launch_bounds__(256, 4) k_alphaM(
    const unsigned int* __restrict__ pairP, const int* __restrict__ gcursor,
    const unsigned short* __restrict__ h16,
    const float* __restrict__ hrW1, const unsigned short* __restrict__ pkWs,
    const float* __restrict__ ww1, const float* __restrict__ wb1,
    float* __restrict__ alphaS)
{
  const int t = threadIdx.x;
  const int w = t >> 6, l = t & 63;
  const int lr = l & 15, lg = l >> 4;
  const int i0 = (blockIdx.x*4 + w) * 16;      // N_SLOT = 64 * gridDim
  const int bkt   = i0 >> 13;                  // MAXCB = 8192 slots/bucket
  const int local = i0 & (MAXCB-1);
  const int size  = min(gcursor[bkt], LCAP);
  if (local >= size) return;                   // wave-uniform

  unsigned pe = pairP[i0 + lr];
  int subA = min((int)(pe & 0x1FFFFu), N_NODE-1);
  bf16x8 a0 = *(const bf16x8*)(h16 + (size_t)subA*HID + lg*8);
  bf16x8 a1 = *(const bf16x8*)(h16 + (size_t)subA*HID + 32 + lg*8);

  bf16x8 b00 = *(const bf16x8*)(pkWs + (size_t)(0*64 + l)*8);
  bf16x8 b01 = *(const bf16x8*)(pkWs + (size_t)(1*64 + l)*8);
  bf16x8 b10 = *(const bf16x8*)(pkWs + (size_t)(2*64 + l)*8);
  bf16x8 b11 = *(const bf16x8*)(pkWs + (size_t)(3*64 + l)*8);

  f32x4 acc0 = {0.f,0.f,0.f,0.f}, acc1 = {0.f,0.f,0.f,0.f};
  acc0 = __builtin_amdgcn_mfma_f32_16x16x32_bf16(a0, b00, acc0, 0,0,0);
  acc0 = __builtin_amdgcn_mfma_f32_16x16x32_bf16(a1, b01, acc0, 0,0,0);
  acc1 = __builtin_amdgcn_mfma_f32_16x16x32_bf16(a0, b10, acc1, 0,0,0);
  acc1 = __builtin_amdgcn_mfma_f32_16x16x32_bf16(a1, b11, acc1, 0,0,0);

  float wlo = ww1[lr], whi = ww1[16 + lr];
  float bias = wb1[0];
  float s[4];
  #pragma unroll
  for (int r=0;r<4;r++){
    int e = i0 + lg*4 + r;
    int rel = min((int)(pairP[e] >> 17), REL_VOCAB-1);
    float v0 = fmaxf(acc0[r] + hrW1[rel*ATTN + lr],      0.f);
    float v1 = fmaxf(acc1[r] + hrW1[rel*ATTN + 16 + lr], 0.f);
    float p = fmaf(v0, wlo, v1*whi);
    p += __shfl_xor(p, 1);
    p += __shfl_xor(p, 2);
    p += __shfl_xor(p, 4);
    p += __shfl_xor(p, 8);
    s[r] = sigf(p + bias);
  }
  if (lr == 0)
    *(float4*)(alphaS + i0 + lg*4) = make_float4(s[0], s[1], s[2], s[3]);
}

// ---- layer-1 aggregation: wave per NODE PAIR; two independent 4-chain
// streams (adjacent nodes share a bucket -> contiguous stream lines).
// Halves serial depth per wave vs wave-per-node.
__global__ void k_agg1(const int* __restrict__ startArr, const int* __restrict__ endArr,
                       const unsigned int* __restrict__ pairP,
                       const float* __restrict__ alphaS,
                       const unsigned short* __restrict__ h16,
                       const unsigned short* __restrict__ re16,
                       unsigned short* __restrict__ agg16)
{
  int t = blockIdx.x*blockDim.x + threadIdx.x;
  int pr = __builtin_amdgcn_readfirstlane(t >> 6);
  int k = t & 63;
  int nA = pr*2;
  if (nA >= N_NODE) return;
  int nB = nA + 1;                              // N_NODE even -> valid
  int bA = startArr[nA], eA = endArr[nA];
  int bB = startArr[nB], eB = endArr[nB];

  float aA0=0.f, aA1=0.f, aA2=0.f, aA3=0.f;
  float aB0=0.f, aB1=0.f, aB2=0.f, aB3=0.f;
  int iA = bA & ~3, iB = bB & ~3;
  while (iA < eA || iB < eB){                   // wave-uniform
    if (iA < eA){
      uint4  p4 = *(const uint4*)(pairP + iA);
      float4 a4 = *(const float4*)(alphaS + iA);
      int s0 = min((int)(p4.x & 0x1FFFFu), N_NODE-1);
      int s1 = min((int)(p4.y & 0x1FFFFu), N_NODE-1);
      int s2 = min((int)(p4.z & 0x1FFFFu), N_NODE-1);
      int s3 = min((int)(p4.w & 0x1FFFFu), N_NODE-1);
      int r0 = min((int)(p4.x >> 17), REL_VOCAB-1);
      int r1 = min((int)(p4.y >> 17), REL_VOCAB-1);
      int r2 = min((int)(p4.z >> 17), REL_VOCAB-1);
      int r3 = min((int)(p4.w >> 17), REL_VOCAB-1);
      float h0 = bf2f(h16[(size_t)s0*HID + k]);
      float h1 = bf2f(h16[(size_t)s1*HID + k]);
      float h2 = bf2f(h16[(size_t)s2*HID + k]);
      float h3 = bf2f(h16[(size_t)s3*HID + k]);
      float v0 = bf2f(re16[r0*HID + k]);
      float v1 = bf2f(re16[r1*HID + k]);
      float v2 = bf2f(re16[r2*HID + k]);
      float v3 = bf2f(re16[r3*HID + k]);
      float al0 = (iA+0>=bA && iA+0<eA) ? a4.x : 0.f;
      float al1 = (iA+1>=bA && iA+1<eA) ? a4.y : 0.f;
      float al2 = (iA+2>=bA && iA+2<eA) ? a4.z : 0.f;
      float al3 = (iA+3>=bA && iA+3<eA) ? a4.w : 0.f;
      aA0 = fmaf(al0, h0+v0, aA0);
      aA1 = fmaf(al1, h1+v1, aA1);
      aA2 = fmaf(al2, h2+v2, aA2);
      aA3 = fmaf(al3, h3+v3, aA3);
    }
    if (iB < eB){
      uint4  p4 = *(const uint4*)(pairP + iB);
      float4 a4 = *(const float4*)(alphaS + iB);
      int s0 = min((int)(p4.x & 0x1FFFFu), N_NODE-1);
      int s1 = min((int)(p4.y & 0x1FFFFu), N_NODE-1);
      int s2 = min((int)(p4.z & 0x1FFFFu), N_NODE-1);
      int s3 = min((int)(p4.w & 0x1FFFFu), N_NODE-1);
      int r0 = min((int)(p4.x >> 17), REL_VOCAB-1);
      int r1 = min((int)(p4.y >> 17), REL_VOCAB-1);
      int r2 = min((int)(p4.z >> 17), REL_VOCAB-1);
      int r3 = min((int)(p4.w >> 17), REL_VOCAB-1);
      float h0 = bf2f(h16[(size_t)s0*HID + k]);
      float h1 = bf2f(h16[(size_t)s1*HID + k]);
      float h2 = bf2f(h16[(size_t)s2*HID + k]);
      float h3 = bf2f(h16[(size_t)s3*HID + k]);
      float v0 = bf2f(re16[r0*HID + k]);
      float v1 = bf2f(re16[r1*HID + k]);
      float v2 = bf2f(re16[r2*HID + k]);
      float v3 = bf2f(re16[r3*HID + k]);
      float al0 = (iB+0>=bB && iB+0<eB) ? a4.x : 0.f;
      float al1 = (iB+1>=bB && iB+1<eB) ? a4.y : 0.f;
      float al2 = (iB+2>=bB && iB+2<eB) ? a4.z : 0.f;
      float al3 = (iB+3>=bB && iB+3<eB) ? a4.w : 0.f;
      aB0 = fmaf(al0, h0+v0, aB0);
      aB1 = fmaf(al1, h1+v1, aB1);
      aB2 = fmaf(al2, h2+v2, aB2);
      aB3 = fmaf(al3, h3+v3, aB3);
    }
    iA += 4; iB += 4;
  }
  agg16[(size_t)nA*HID + k] = f2bf((aA0+aA1)+(aA2+aA3));
  agg16[(size_t)nB*HID + k] = f2bf((aB0+aB1)+(aB2+aB3));
}

// ---- MFMA node phase: 64 nodes/block, wave w owns nodes w*16..w*16+15 ----
// xlds regions are PER-WAVE private -> no __syncthreads anywhere; waves run
// fully independently (wave_lds_fence orders write->read within the wave).
template<int HAS_H0>
__global__ void __launch_bounds__(256, 4) k_node2(
    const unsigned short* __restrict__ agg16,
    const unsigned short* __restrict__ h16,
    const unsigned short* __restrict__ pkWh,
    const unsigned short* __restrict__ pkWih,
    const unsigned short* __restrict__ pkWhh,
    const float* __restrict__ bih, const float* __restrict__ bhh,
    unsigned short* __restrict__ h16_out,
    const float* __restrict__ wf, float* __restrict__ score, int mode)
{
  __shared__ unsigned short xlds[4096];   // 4 waves x [16 rows][64 cols] bf16, swizzled

  const int t  = threadIdx.x;
  const int w  = t >> 6, l = t & 63;
  const int lr = l & 15;                  // fragment row/col
  const int lg = l >> 4;                  // k-group
  const int n0 = blockIdx.x * 64;
  const int rowA = n0 + w*16 + lr;

  bf16x8 aA0 = *(const bf16x8*)(agg16 + (size_t)rowA*HID + lg*8);
  bf16x8 aA1 = *(const bf16x8*)(agg16 + (size_t)rowA*HID + 32 + lg*8);
  bf16x8 hA0, hA1;
  if (HAS_H0){
    hA0 = *(const bf16x8*)(h16 + (size_t)rowA*HID + lg*8);
    hA1 = *(const bf16x8*)(h16 + (size_t)rowA*HID + 32 + lg*8);
  }

  float bir[4],biz[4],bin[4],bhr[4],bhz[4],bhn[4],wfv[4];
  #pragma unroll
  for (int nt=0;nt<4;nt++){
    int ch = nt*16 + lr;
    bir[nt]=bih[ch]; biz[nt]=bih[64+ch]; bin[nt]=bih[128+ch];
    bhr[nt]=bhh[ch]; bhz[nt]=bhh[64+ch]; bhn[nt]=bhh[128+ch];
    wfv[nt]=wf[ch];
  }

  // ---- X = relu(agg @ Wh^T) ----
  #pragma unroll
  for (int nt=0;nt<4;nt++){
    f32x4 acc = {0.f,0.f,0.f,0.f};
    bf16x8 b0 = *(const bf16x8*)(pkWh + (size_t)((nt*2+0)*64 + l)*8);
    bf16x8 b1 = *(const bf16x8*)(pkWh + (size_t)((nt*2+1)*64 + l)*8);
    acc = __builtin_amdgcn_mfma_f32_16x16x32_bf16(aA0, b0, acc, 0,0,0);
    acc = __builtin_amdgcn_mfma_f32_16x16x32_bf16(aA1, b1, acc, 0,0,0);
    #pragma unroll
    for (int r=0;r<4;r++){
      int m = lg*4 + r, col = nt*16 + lr;
      xlds[w*1024 + m*64 + (col ^ ((m&7)<<3))] = f2bf(fmaxf(acc[r], 0.f));
    }
  }
  wave_lds_fence();

  const int xbase = w*1024 + lr*64;
  const int sw = (lr&7)<<3;
  bf16x8 xA0 = *(const bf16x8*)&xlds[xbase + ((lg*8)      ^ sw)];
  bf16x8 xA1 = *(const bf16x8*)&xlds[xbase + ((32 + lg*8) ^ sw)];

  // ---- gate passes ----
  float rv[16], zv[16], hv[16];
  #pragma unroll
  for (int g=0; g<2; ++g){               // g=0: r-gate, g=1: z-gate
    #pragma unroll
    for (int nt=0;nt<4;nt++){
      int gt = g*4 + nt;
      f32x4 ai = {0.f,0.f,0.f,0.f};
      bf16x8 bi0 = *(const bf16x8*)(pkWih + (size_t)((gt*2+0)*64 + l)*8);
      bf16x8 bi1 = *(const bf16x8*)(pkWih + (size_t)((gt*2+1)*64 + l)*8);
      ai = __builtin_amdgcn_mfma_f32_16x16x32_bf16(xA0, bi0, ai, 0,0,0);
      ai = __builtin_amdgcn_mfma_f32_16x16x32_bf16(xA1, bi1, ai, 0,0,0);
      f32x4 ah = {0.f,0.f,0.f,0.f};
      if (HAS_H0){
        bf16x8 bh0 = *(const bf16x8*)(pkWhh + (size_t)((gt*2+0)*64 + l)*8);
        bf16x8 bh1 = *(const bf16x8*)(pkWhh + (size_t)((gt*2+1)*64 + l)*8);
        ah = __builtin_amdgcn_mfma_f32_16x16x32_bf16(hA0, bh0, ah, 0,0,0);
        ah = __builtin_amdgcn_mfma_f32_16x16x32_bf16(hA1, bh1, ah, 0,0,0);
      }
      #pragma unroll
      for (int r=0;r<4;r++){
        float bi_ = (g==0) ? bir[nt] : biz[nt];
        float bh_ = (g==0) ? bhr[nt] : bhz[nt];
        float v = sigf(ai[r] + bi_ + ah[r] + bh_);
        if (g==0) rv[nt*4+r] = v; else zv[nt*4+r] = v;
      }
    }
  }
  #pragma unroll
  for (int nt=0;nt<4;nt++){              // n-gate + GRU blend
    int gt = 8 + nt;
    f32x4 ai = {0.f,0.f,0.f,0.f};
    bf16x8 bi0 = *(const bf16x8*)(pkWih + (size_t)((gt*2+0)*64 + l)*8);
    bf16x8 bi1 = *(const bf16x8*)(pkWih + (size_t)((gt*2+1)*64 + l)*8);
    ai = __builtin_amdgcn_mfma_f32_16x16x32_bf16(xA0, bi0, ai, 0,0,0);
    ai = __builtin_amdgcn_mfma_f32_16x16x32_bf16(xA1, bi1, ai, 0,0,0);
    f32x4 ah = {0.f,0.f,0.f,0.f};
    if (HAS_H0){
      bf16x8 bh0 = *(const bf16x8*)(pkWhh + (size_t)((gt*2+0)*64 + l)*8);
      bf16x8 bh1 = *(const bf16x8*)(pkWhh + (size_t)((gt*2+1)*64 + l)*8);
      ah = __builtin_amdgcn_mfma_f32_16x16x32_bf16(hA0, bh0, ah, 0,0,0);
      ah = __builtin_amdgcn_mfma_f32_16x16x32_bf16(hA1, bh1, ah, 0,0,0);
    }
    #pragma unroll
    for (int r=0;r<4;r++){
      float gin = ai[r] + bin[nt];
      float ghn = ah[r] + bhn[nt];
      float rr  = rv[nt*4+r];
      float nn  = tanh_fast(fmaf(rr, ghn, gin));
      float z   = zv[nt*4+r];
      float h0v = 0.f;
      if (HAS_H0)
        h0v = bf2f(h16[(size_t)(n0 + w*16 + lg*4 + r)*HID + nt*16 + lr]);
      hv[nt*4+r] = (1.f - z)*nn + z*h0v;
    }
  }

  if (mode == 0){
    // xA0/xA1 already hold all xlds data this wave needs; safe to overwrite
    // own region (in-wave DS ordering + compiler alias ordering).
    #pragma unroll
    for (int nt=0;nt<4;nt++)
      #pragma unroll
      for (int r=0;r<4;r++){
        int m = lg*4 + r, col = nt*16 + lr;
        xlds[w*1024 + m*64 + (col ^ ((m&7)<<3))] = f2bf(hv[nt*4+r]);
      }
    wave_lds_fence();
    int rr2 = l >> 2, cc = l & 3;
    int n = n0 + w*16 + rr2;
    if (n < N_NODE){
      int base = w*1024 + rr2*64, s2 = (rr2&7)<<3;
      bf16x8 v0 = *(const bf16x8*)&xlds[base + ((cc*16)     ^ s2)];
      bf16x8 v1 = *(const bf16x8*)&xlds[base + ((cc*16 + 8) ^ s2)];
      *(bf16x8*)(h16_out + (size_t)n*HID + cc*16)     = v0;
      *(bf16x8*)(h16_out + (size_t)n*HID + cc*16 + 8) = v1;
    }
  } else {
    #pragma unroll
    for (int r=0;r<4;r++){
      float p = 0.f;
      #pragma unroll
      for (int nt=0;nt<4;nt++) p = fmaf(hv[nt*4+r], wfv[nt], p);
      p += __shfl_xor(p, 1);
      p += __shfl_xor(p, 2);
      p += __shfl_xor(p, 4);
      p += __shfl_xor(p, 8);
      if (lr == 0){
        int n = n0 + w*16 + lg*4 + r;
        if (n < N_NODE) score[n] = p;
      }
    }
  }
}

extern "C" void kernel_launch(void* const* d_in, const int* in_sizes, int n_in,
                              void* d_out, int out_size, void* d_ws, size_t ws_size,
                              hipStream_t stream)
{
  const int*   edges = (const int*)  d_in[0];
  const float* re    = (const float*)d_in[1];
  const float* Ws    = (const float*)d_in[2];
  const float* Wr    = (const float*)d_in[3];
  const float* ww    = (const float*)d_in[4];
  const float* wb    = (const float*)d_in[5];
  const float* Wh    = (const float*)d_in[6];
  const float* Wih   = (const float*)d_in[7];
  const float* Whh   = (const float*)d_in[8];
  const float* bih   = (const float*)d_in[9];
  const float* bhh   = (const float*)d_in[10];
  const float* wf    = (const float*)d_in[11];
  float* out = (float*)d_out;

  // workspace layout
  unsigned short* agg16  = (unsigned short*)d_ws;              // N_PAD*HID
  unsigned short* h16    = agg16 + (size_t)N_PAD*HID;          // N_PAD*HID
  unsigned short* srel16 = h16 + (size_t)N_PAD*HID;            // REL_VOCAB*HID
  unsigned short* re16   = srel16 + REL_VOCAB*HID;             // REL_VOCAB*HID
  unsigned short* pkWh   = re16 + REL_VOCAB*HID;               // 2*4096
  unsigned short* pkWih  = pkWh  + 2*4096;                     // 2*12288
  unsigned short* pkWhh  = pkWih + 2*12288;                    // 2*12288
  unsigned short* pkWs   = pkWhh + 2*12288;                    // 2048
  float* hrW1      = (float*)(pkWs + 2048);                    // REL_VOCAB*ATTN
  float* alphaS    = hrW1 + REL_VOCAB*ATTN;                    // N_SLOT
  uint2* tmp       = (uint2*)(alphaS + N_SLOT);                // N_SLOT uint2
  unsigned int* pairP = (unsigned int*)(tmp + N_SLOT);         // N_SLOT uint
  int*   startArr  = (int*)(pairP + N_SLOT);                   // NCB*CBN
  int*   endArr    = startArr + NCB*CBN;                       // NCB*CBN
  int*   gcursor   = endArr + NCB*CBN;                         // 256 (pad)

  // ---- two-pass bucket sort of edges by obj ----
  k_izero<<<1, 256, 0, stream>>>(gcursor, 256);
  k_part<<<(N_EDGE + ACHUNK - 1)/ACHUNK, 256, 0, stream>>>(edges, gcursor, tmp);
  k_bsort2<<<NCB, 256, 0, stream>>>(tmp, gcursor, pairP, startArr, endArr);

  // ---- per-relation tables + packed bf16 weights ----
  k_pre<<<(REL_VOCAB*64+255)/256, 256, 0, stream>>>(re, Wr, ww, wb, srel16, re16, hrW1);
  k_wt<<<(116*64+255)/256, 256, 0, stream>>>(Wh, Wih, Whh, Ws, pkWh, pkWih, pkWhh, pkWs);

  const int NB_NODE2 = (N_NODE + 63) / 64;

  // ---- layer 0 ----
  k_agg0<<<(N_NODE*64)/256, 256, 0, stream>>>(startArr, endArr, pairP, srel16, agg16);
  k_node2<0><<<NB_NODE2, 256, 0, stream>>>(agg16, h16,
        pkWh, pkWih, pkWhh, bih, bhh, h16, wf, out, 0);

  // ---- layer 1 ----
  k_alphaM<<<N_SLOT/64, 256, 0, stream>>>(pairP, gcursor, h16, hrW1, pkWs,
        ww + ATTN, wb + 1, alphaS);
  k_agg1<<<(N_NODE/2*64)/256, 256, 0, stream>>>(startArr, endArr, pairP, alphaS,
        h16, re16, agg16);
  k_node2<1><<<NB_NODE2, 256, 0, stream>>>(agg16, h16,
        pkWh + 4096, pkWih + 12288, pkWhh + 12288, bih + 3*HID, bhh + 3*HID,
        h16, wf, out, 1);
}